// Round 6
// baseline (2285.181 us; speedup 1.0000x reference)
//
#include <hip/hip_runtime.h>
#include <hip/hip_bf16.h>

#define B_    64
#define NP_   196
#define NVIS_ 49
#define D_    384
#define DD_   256
#define SENC_ 50
#define SDEC_ 196

typedef __hip_bfloat16 bf16;
typedef __attribute__((ext_vector_type(8))) short short8;
typedef __attribute__((ext_vector_type(4))) float float4v;

__device__ __forceinline__ float bf2f(bf16 x) { return __bfloat162float(x); }
__device__ __forceinline__ bf16 f2bf(float x) { return __float2bfloat16(x); }
__device__ __forceinline__ float rdin(const void* p, long i, int f) {
  return f ? ((const float*)p)[i] : bf2f(((const bf16*)p)[i]);
}

// ---- dtype probe ----
__global__ void probe_kernel(const void* w, int* flag) {
  int tid = threadIdx.x;
  float mx = 0.f;
  for (int i = tid; i < 512; i += 64)
    mx = fmaxf(mx, fabsf(bf2f(((const bf16*)w)[i])));
#pragma unroll
  for (int off = 32; off; off >>= 1) mx = fmaxf(mx, __shfl_xor(mx, off));
  if (tid == 0) *flag = (mx > 1e3f) ? 1 : 0;  // 1 => inputs are fp32
}

__global__ __launch_bounds__(256) void fill_kernel(bf16* out, float v, int n) {
  int idx = blockIdx.x * 256 + threadIdx.x;
  if (idx < n) out[idx] = f2bf(v);
}

// ---------------- im2col over VISIBLE patches only -> bf16 ----------------
__global__ __launch_bounds__(256) void im2col_vis_kernel(
    const void* __restrict__ x, const int* __restrict__ unmasked,
    bf16* __restrict__ out, const int* __restrict__ dflag) {
  int f = *dflag;
  int idx = blockIdx.x * 256 + threadIdx.x;
  const int TOT = B_ * NVIS_ * 768;
  if (idx >= TOT) return;
  int k = idx % 768;
  int row = idx / 768;
  int j = row % NVIS_;
  int b = row / NVIS_;
  int n = unmasked[b * NVIS_ + j];
  int ph = n / 14, pw = n % 14;
  int c  = k >> 8;
  int rr = (k >> 4) & 15;
  int cc = k & 15;
  out[idx] = f2bf(rdin(x, (long)(((b * 3 + c) * 224) + ph * 16 + rr) * 224 + pw * 16 + cc, f));
}

// ---- MFMA GEMM, BK=64, double-buffered LDS + register prefetch -----------
// C[M,N] = epi(A[M,K](bf16) @ W[N,K]^T + bias); wave tile TMW x TNW, 2x2 waves.
// MODE 0 plain, 1 exact GELU, 2 += res(f32).
// out_mode: 0 bf16, 1 f32, 2 per dtype flag.
// grid.z = split-K count; if >1, writes fp32 partials to pbuf (no epilogue).
// M%(2TMW)==0, N%(2TNW)==0, (K/grid.z)%64==0.
#define LDKE 72  // LDS row stride (elements); stage writes conflict-free, frag reads 2-way
template <int MODE, int TMW, int TNW>
__global__ __launch_bounds__(256) void gemm_kernel(
    const bf16* __restrict__ A, const void* __restrict__ W, long wOff,
    const void* __restrict__ bias, long bOff, const float* __restrict__ res,
    void* __restrict__ C, float* __restrict__ pbuf,
    int M, int N, int K, int out_mode, const int* __restrict__ dflag) {
  constexpr int BM = 2 * TMW, BN = 2 * TNW;
  constexpr int AM = TMW / 16, AN = TNW / 16;
  constexpr int APASS = BM / 32, WPASS = BN / 32;
  int f = *dflag;
  __shared__ bf16 Asl[2][BM * LDKE];
  __shared__ bf16 Bsl[2][BN * LDKE];
  int tid = threadIdx.x;
  int bx = blockIdx.x, by = blockIdx.y, bz = blockIdx.z;
  int w = tid >> 6, lane = tid & 63, quad = lane >> 4, l16 = lane & 15;
  int wm = (w & 1) * TMW, wn = (w >> 1) * TNW;
  int Ks = K / gridDim.z;
  const bf16* Ab = A + (long)by * BM * K + (long)bz * Ks;
  long wBase = wOff + (long)bx * BN * K + (long)bz * Ks;
  int arow = tid >> 3, achk = tid & 7;  // 32 rows x 8 chunks(16B) per pass

  uint4 pa[APASS];
  uint4 pwb[WPASS];
  float4 pw0[WPASS], pw1[WPASS];

  auto loadA = [&](int k0) {
#pragma unroll
    for (int p = 0; p < APASS; p++) {
      int r = arow + p * 32;
      pa[p] = *(const uint4*)(Ab + (long)r * K + k0 + achk * 8);
    }
  };
  auto loadW = [&](int k0) {
    if (f) {
#pragma unroll
      for (int p = 0; p < WPASS; p++) {
        int r = arow + p * 32;
        const float* q = (const float*)W + wBase + (long)r * K + k0 + achk * 8;
        pw0[p] = *(const float4*)q;
        pw1[p] = *(const float4*)(q + 4);
      }
    } else {
#pragma unroll
      for (int p = 0; p < WPASS; p++) {
        int r = arow + p * 32;
        pwb[p] = *(const uint4*)((const bf16*)W + wBase + (long)r * K + k0 + achk * 8);
      }
    }
  };
  auto storeTile = [&](int buf) {
#pragma unroll
    for (int p = 0; p < APASS; p++) {
      int r = arow + p * 32;
      *(uint4*)(&Asl[buf][r * LDKE + achk * 8]) = pa[p];
    }
    if (f) {
#pragma unroll
      for (int p = 0; p < WPASS; p++) {
        int r = arow + p * 32;
        union { uint4 u; bf16 hh[8]; } pk;
        pk.hh[0] = f2bf(pw0[p].x); pk.hh[1] = f2bf(pw0[p].y);
        pk.hh[2] = f2bf(pw0[p].z); pk.hh[3] = f2bf(pw0[p].w);
        pk.hh[4] = f2bf(pw1[p].x); pk.hh[5] = f2bf(pw1[p].y);
        pk.hh[6] = f2bf(pw1[p].z); pk.hh[7] = f2bf(pw1[p].w);
        *(uint4*)(&Bsl[buf][r * LDKE + achk * 8]) = pk.u;
      }
    } else {
#pragma unroll
      for (int p = 0; p < WPASS; p++) {
        int r = arow + p * 32;
        *(uint4*)(&Bsl[buf][r * LDKE + achk * 8]) = pwb[p];
      }
    }
  };

  float4v acc[AM][AN];
#pragma unroll
  for (int i = 0; i < AM; i++)
#pragma unroll
    for (int j = 0; j < AN; j++) acc[i][j] = (float4v){0.f, 0.f, 0.f, 0.f};

  int NIT = Ks / 64;
  loadA(0); loadW(0); storeTile(0);
  __syncthreads();
  for (int it = 0; it < NIT; it++) {
    int cur = it & 1;
    if (it + 1 < NIT) { loadA((it + 1) * 64); loadW((it + 1) * 64); }
#pragma unroll
    for (int kh = 0; kh < 2; kh++) {
      short8 af[AM], bfr[AN];
#pragma unroll
      for (int mi = 0; mi < AM; mi++)
        af[mi] = *(const short8*)&Asl[cur][(wm + mi * 16 + l16) * LDKE + kh * 32 + quad * 8];
#pragma unroll
      for (int ni = 0; ni < AN; ni++)
        bfr[ni] = *(const short8*)&Bsl[cur][(wn + ni * 16 + l16) * LDKE + kh * 32 + quad * 8];
#pragma unroll
      for (int mi = 0; mi < AM; mi++)
#pragma unroll
        for (int ni = 0; ni < AN; ni++)
          acc[mi][ni] = __builtin_amdgcn_mfma_f32_16x16x32_bf16(
              af[mi], bfr[ni], acc[mi][ni], 0, 0, 0);
    }
    if (it + 1 < NIT) storeTile(1 - cur);
    __syncthreads();
  }

  if (gridDim.z == 1) {
    int om = (out_mode == 2) ? (f ? 1 : 0) : out_mode;  // 1=f32, 0=bf16
#pragma unroll
    for (int mi = 0; mi < AM; mi++) {
#pragma unroll
      for (int ni = 0; ni < AN; ni++) {
        int cn = bx * BN + wn + ni * 16 + l16;
        float bval = rdin(bias, bOff + cn, f);
#pragma unroll
        for (int r = 0; r < 4; r++) {
          int cm = by * BM + wm + mi * 16 + quad * 4 + r;
          float v = acc[mi][ni][r] + bval;
          if constexpr (MODE == 1) v = 0.5f * v * (1.0f + erff(v * 0.70710678f));
          if constexpr (MODE == 2) v += res[(long)cm * N + cn];
          if (om) ((float*)C)[(long)cm * N + cn] = v;
          else    ((bf16*)C)[(long)cm * N + cn] = f2bf(v);
        }
      }
    }
  } else {
    float* P = pbuf + (long)bz * M * N;
#pragma unroll
    for (int mi = 0; mi < AM; mi++)
#pragma unroll
      for (int ni = 0; ni < AN; ni++) {
        int cn = bx * BN + wn + ni * 16 + l16;
#pragma unroll
        for (int r = 0; r < 4; r++) {
          int cm = by * BM + wm + mi * 16 + quad * 4 + r;
          P[(long)cm * N + cn] = acc[mi][ni][r];
        }
      }
  }
}

// ---- split-K reduce + epilogue ----
template <int MODE>
__global__ __launch_bounds__(256) void sk_reduce_kernel(
    const float* __restrict__ pbuf, int S, long MN, int N,
    const void* __restrict__ bias, long bOff, const float* __restrict__ res,
    void* __restrict__ C, int out_mode, const int* __restrict__ dflag) {
  int f = *dflag;
  long i4 = ((long)blockIdx.x * 256 + threadIdx.x) * 4;
  if (i4 >= MN) return;
  float4 v = {0.f, 0.f, 0.f, 0.f};
  for (int z = 0; z < S; z++) {
    float4 p = *(const float4*)(pbuf + z * MN + i4);
    v.x += p.x; v.y += p.y; v.z += p.z; v.w += p.w;
  }
  int cn = (int)(i4 % N);
  float vv[4] = {v.x, v.y, v.z, v.w};
  int om = (out_mode == 2) ? (f ? 1 : 0) : out_mode;
#pragma unroll
  for (int j = 0; j < 4; j++) {
    float t = vv[j] + rdin(bias, bOff + cn + j, f);
    if constexpr (MODE == 1) t = 0.5f * t * (1.0f + erff(t * 0.70710678f));
    if constexpr (MODE == 2) t += res[i4 + j];
    if (om) ((float*)C)[i4 + j] = t;
    else    ((bf16*)C)[i4 + j] = f2bf(t);
  }
}

// ---------------- LayerNorm: one wave per row, f32 -> bf16 ----------------
template <int N>
__global__ __launch_bounds__(256) void ln_kernel(
    const float* __restrict__ X, const void* __restrict__ w, long wOff,
    const void* __restrict__ bv, long bOff, bf16* __restrict__ Y, int M,
    const int* __restrict__ dflag) {
  int f = *dflag;
  int row = blockIdx.x * 4 + (threadIdx.x >> 6);
  int lane = threadIdx.x & 63;
  if (row >= M) return;
  const float* xr = X + (long)row * N;
  constexpr int CNT = N / 64;
  float v[CNT];
  float sum = 0.f;
#pragma unroll
  for (int i = 0; i < CNT; i++) { v[i] = xr[lane + 64 * i]; sum += v[i]; }
#pragma unroll
  for (int off = 32; off; off >>= 1) sum += __shfl_xor(sum, off);
  float mean = sum * (1.0f / N);
  float vs = 0.f;
#pragma unroll
  for (int i = 0; i < CNT; i++) { float d = v[i] - mean; vs += d * d; }
#pragma unroll
  for (int off = 32; off; off >>= 1) vs += __shfl_xor(vs, off);
  float rstd = rsqrtf(vs * (1.0f / N) + 1e-5f);
  bf16* yr = Y + (long)row * N;
#pragma unroll
  for (int i = 0; i < CNT; i++) {
    int cidx = lane + 64 * i;
    yr[cidx] = f2bf((v[i] - mean) * rstd * rdin(w, wOff + cidx, f) + rdin(bv, bOff + cidx, f));
  }
}

// ---- decoder attention, MFMA flash: S=196, DH=32, H=8 --------------------
__global__ __launch_bounds__(256) void attn_dec_kernel(
    const bf16* __restrict__ qkv, bf16* __restrict__ out) {
  const int S = SDEC_, DH = 32, Dm = 256, tri = 768;
  const int KLD = 40, VLD = 232, PLD = 232;
  int b = blockIdx.x >> 3, h = blockIdx.x & 7;
  __shared__ bf16 Ksh[208 * KLD];
  __shared__ bf16 Vt[32 * VLD];
  __shared__ bf16 Psh[4][16 * PLD];
  int tid = threadIdx.x;
  const bf16* base = qkv + (long)b * S * tri;
  for (int idx = tid; idx < S * 4; idx += 256) {
    int s = idx >> 2, part = (idx & 3) * 8;
    uint4 v = *(const uint4*)(base + (long)s * tri + Dm + h * DH + part);
    *(uint4*)(&Ksh[s * KLD + part]) = v;
  }
  if (tid < 12 * 4) {
    int s = 196 + (tid >> 2), part = (tid & 3) * 8;
    uint4 z = {0, 0, 0, 0};
    *(uint4*)(&Ksh[s * KLD + part]) = z;
  }
  for (int idx = tid; idx < S * DH; idx += 256) {
    int s = idx >> 5, d = idx & 31;
    Vt[d * VLD + s] = base[(long)s * tri + 2 * Dm + h * DH + d];
  }
  for (int idx = tid; idx < 32 * 36; idx += 256) {
    int d = idx / 36, c = 196 + idx % 36;
    Vt[d * VLD + c] = f2bf(0.f);
  }
  __syncthreads();
  int w = tid >> 6, lane = tid & 63, l16 = lane & 15, quad = lane >> 4;
  bf16* Pw = &Psh[w][0];
  const float scale = 0.17677669529663687f;
  for (int qt = w; qt < 13; qt += 4) {
    int q0 = qt * 16;
    int qr = min(q0 + l16, S - 1);
    short8 qf = *(const short8*)(base + (long)qr * tri + h * DH + quad * 8);
    float4v sc[13];
#pragma unroll
    for (int t = 0; t < 13; t++) {
      short8 kf = *(const short8*)&Ksh[(t * 16 + l16) * KLD + quad * 8];
      sc[t] = __builtin_amdgcn_mfma_f32_16x16x32_bf16(
          qf, kf, (float4v){0.f, 0.f, 0.f, 0.f}, 0, 0, 0);
    }
    float mx[4] = {-1e30f, -1e30f, -1e30f, -1e30f};
#pragma unroll
    for (int t = 0; t < 13; t++) {
      bool valid = (t * 16 + l16) < S;
#pragma unroll
      for (int r = 0; r < 4; r++) {
        float v = valid ? sc[t][r] * scale : -1e30f;
        sc[t][r] = v;
        mx[r] = fmaxf(mx[r], v);
      }
    }
#pragma unroll
    for (int off = 1; off < 16; off <<= 1)
#pragma unroll
      for (int r = 0; r < 4; r++) mx[r] = fmaxf(mx[r], __shfl_xor(mx[r], off));
    float sm[4] = {0.f, 0.f, 0.f, 0.f};
#pragma unroll
    for (int t = 0; t < 13; t++)
#pragma unroll
      for (int r = 0; r < 4; r++) {
        float p = __expf(sc[t][r] - mx[r]);
        sc[t][r] = p;
        sm[r] += p;
      }
#pragma unroll
    for (int off = 1; off < 16; off <<= 1)
#pragma unroll
      for (int r = 0; r < 4; r++) sm[r] += __shfl_xor(sm[r], off);
#pragma unroll
    for (int t = 0; t < 14; t++) {
      int col = t * 16 + l16;
#pragma unroll
      for (int r = 0; r < 4; r++) {
        float p = (t < 13) ? sc[t][r] : 0.f;
        Pw[(quad * 4 + r) * PLD + col] = f2bf(p);
      }
    }
    __asm__ volatile("s_waitcnt lgkmcnt(0)" ::: "memory");
    float4v o0 = {0.f, 0.f, 0.f, 0.f}, o1 = {0.f, 0.f, 0.f, 0.f};
#pragma unroll
    for (int kc = 0; kc < 7; kc++) {
      short8 pf = *(const short8*)&Pw[l16 * PLD + kc * 32 + quad * 8];
      short8 v0 = *(const short8*)&Vt[l16 * VLD + kc * 32 + quad * 8];
      short8 v1 = *(const short8*)&Vt[(16 + l16) * VLD + kc * 32 + quad * 8];
      o0 = __builtin_amdgcn_mfma_f32_16x16x32_bf16(pf, v0, o0, 0, 0, 0);
      o1 = __builtin_amdgcn_mfma_f32_16x16x32_bf16(pf, v1, o1, 0, 0, 0);
    }
#pragma unroll
    for (int r = 0; r < 4; r++) {
      int row = q0 + quad * 4 + r;
      if (row < S) {
        float inv = 1.f / sm[r];
        bf16* op = out + ((long)(b * S + row)) * Dm + h * DH;
        op[l16]      = f2bf(o0[r] * inv);
        op[16 + l16] = f2bf(o1[r] * inv);
      }
    }
  }
}

// ---- encoder attention: S=50, DH=64, H=6. 128 thr = 2 waves, j-split ------
__global__ __launch_bounds__(128) void attn_enc_kernel(
    const bf16* __restrict__ qkv, bf16* __restrict__ out) {
  const int S = SENC_, H = 6, DH = 64, Dm = H * DH, tri = 3 * Dm;
  int b = blockIdx.x / H, h = blockIdx.x % H;
  int tid = threadIdx.x;
  __shared__ float Ks[SENC_ * 64];
  __shared__ float Vs[SENC_ * 64];
  __shared__ float P1[SENC_ * 66];
  const bf16* base = qkv + (long)b * S * tri;
  for (int idx = tid; idx < S * 8; idx += 128) {
    int s = idx >> 3, part = (idx & 7) * 8;
    union { uint4 u; bf16 hh[8]; } kk, vv;
    kk.u = *(const uint4*)(base + (long)s * tri + Dm + h * DH + part);
    vv.u = *(const uint4*)(base + (long)s * tri + 2 * Dm + h * DH + part);
#pragma unroll
    for (int j = 0; j < 8; j++) {
      Ks[s * DH + part + j] = bf2f(kk.hh[j]);
      Vs[s * DH + part + j] = bf2f(vv.hh[j]);
    }
  }
  __syncthreads();
  int w = tid >> 6, lane = tid & 63;
  int row = lane;
  float q[DH], o[DH];
  float m = -1e30f, l = 0.f;
  if (lane < S) {
    const float scale = 0.125f;
#pragma unroll
    for (int d = 0; d < DH; d++) {
      q[d] = bf2f(base[(long)row * tri + h * DH + d]) * scale;
      o[d] = 0.f;
    }
    int jlo = w * 25, jhi = jlo + 25;
    for (int j = jlo; j < jhi; j++) {
      float s = 0.f;
#pragma unroll
      for (int d = 0; d < DH; d++) s += q[d] * Ks[j * DH + d];
      float mn = fmaxf(m, s);
      float corr = __expf(m - mn);
      float p = __expf(s - mn);
      l = l * corr + p;
      m = mn;
#pragma unroll
      for (int d = 0; d < DH; d++) o[d] = o[d] * corr + p * Vs[j * DH + d];
    }
    if (w == 1) {
#pragma unroll
      for (int d = 0; d < DH; d++) P1[row * 66 + d] = o[d];
      P1[row * 66 + 64] = m;
      P1[row * 66 + 65] = l;
    }
  }
  __syncthreads();
  if (w == 0 && lane < S) {
    float m1 = P1[row * 66 + 64], l1 = P1[row * 66 + 65];
    float mg = fmaxf(m, m1);
    float e0 = __expf(m - mg), e1 = __expf(m1 - mg);
    float lg = l * e0 + l1 * e1;
    float inv = 1.f / lg;
    bf16* op = out + ((long)(b * S + row) * Dm + h * DH);
#pragma unroll
    for (int d = 0; d < DH; d++)
      op[d] = f2bf((o[d] * e0 + P1[row * 66 + d] * e1) * inv);
  }
}

// ---------------- small elementwise kernels ----------------
__global__ __launch_bounds__(256) void build_xe_kernel(
    const bf16* __restrict__ vis, const void* __restrict__ cls,
    const void* __restrict__ pos, const int* __restrict__ unmasked,
    float* __restrict__ xe, const int* __restrict__ dflag) {
  int f = *dflag;
  int idx = blockIdx.x * 256 + threadIdx.x;
  const int TOT = B_ * SENC_ * D_;
  if (idx >= TOT) return;
  int d = idx % D_;
  int s = (idx / D_) % SENC_;
  int b = idx / (D_ * SENC_);
  float v;
  if (s == 0) {
    v = rdin(cls, d, f) + rdin(pos, d, f);
  } else {
    int j = s - 1;
    int n = unmasked[b * NVIS_ + j];
    v = bf2f(vis[(long)(b * NVIS_ + j) * D_ + d]) + rdin(pos, (long)(1 + n) * D_ + d, f);
  }
  xe[idx] = v;
}

__global__ __launch_bounds__(256) void dec_init_kernel(
    const void* __restrict__ mask_token, const void* __restrict__ dpos,
    float* __restrict__ full, const int* __restrict__ dflag) {
  int f = *dflag;
  int idx = blockIdx.x * 256 + threadIdx.x;
  const int TOT = B_ * NP_ * DD_;
  if (idx >= TOT) return;
  int d = idx % DD_;
  int n = (idx / DD_) % NP_;
  full[idx] = rdin(mask_token, d, f) + rdin(dpos, (long)(1 + n) * DD_ + d, f);
}

__global__ __launch_bounds__(256) void dec_scatter_kernel(
    const bf16* __restrict__ xd, const int* __restrict__ unmasked,
    const void* __restrict__ dpos, float* __restrict__ full,
    const int* __restrict__ dflag) {
  int f = *dflag;
  int idx = blockIdx.x * 256 + threadIdx.x;
  const int TOT = B_ * NVIS_ * DD_;
  if (idx >= TOT) return;
  int d = idx % DD_;
  int j = (idx / DD_) % NVIS_;
  int b = idx / (DD_ * NVIS_);
  int n = unmasked[b * NVIS_ + j];
  full[((long)(b * NP_ + n)) * DD_ + d] =
      bf2f(xd[((long)(b * SENC_ + 1 + j)) * DD_ + d]) + rdin(dpos, (long)(1 + n) * DD_ + d, f);
}

// ---------------- host ----------------
extern "C" void kernel_launch(void* const* d_in, const int* in_sizes, int n_in,
                              void* d_out, int out_size, void* d_ws, size_t ws_size,
                              hipStream_t stream) {
  (void)in_sizes; (void)n_in;
  const int* unmasked = (const int*)d_in[1];
  const int M_ENC = B_ * SENC_;  // 3200
  const int M_DEC = B_ * NP_;    // 12544
  const int M_VIS = B_ * NVIS_;  // 3136

  // ws: prior layout (58,884,096) + pbuf 19,660,800 + dflag
  const size_t NEEDED = 78544900;
  if (ws_size < NEEDED) {
    fill_kernel<<<(out_size + 255) / 256, 256, 0, stream>>>(
        (bf16*)d_out, (float)(ws_size >> 20), out_size);
    return;
  }
  char* wsb = (char*)d_ws;
  bf16*  big    = (bf16*)wsb;                 // 12544*1024 bf16 = 25,690,112
  bf16*  t0     = (bf16*)(wsb + 25690112);    // 12544*256  bf16 =  6,422,528
  float* xe     = (float*)(wsb + 32112640);   // 3200*384 f32    =  4,915,200
  float* full   = (float*)(wsb + 37027840);   // 12544*256 f32   = 12,845,056
  bf16*  im2col = (bf16*)(wsb + 49872896);    // 3136*768 bf16
  bf16*  vis    = (bf16*)(wsb + 54788096);    // 3200*384 bf16
  bf16*  xd     = (bf16*)(wsb + 57245696);    // 3200*256 bf16
  float* pbuf   = (float*)(wsb + 58884096);   // 4*3200*384 f32 max = 19,660,800
  int*   dflag  = (int*)(wsb + 78544896);

  probe_kernel<<<1, 64, 0, stream>>>(d_in[3], dflag);

  // cfg: 1 -> 128x64 block (waves 64x32), 2 -> 64x64 block (waves 32x32)
  auto gemm = [&](int mode, int cfg, int S, const bf16* A, const void* W, long wOff,
                  const void* bias, long bOff, const float* res, void* C,
                  int M, int N, int K, int out_mode) {
    int BM = (cfg == 2) ? 64 : 128;
    int BN = 64;
    dim3 g(N / BN, M / BM, S);
#define GL(MO, TM, TN) gemm_kernel<MO, TM, TN><<<g, 256, 0, stream>>>( \
        A, W, wOff, bias, bOff, res, C, pbuf, M, N, K, out_mode, dflag)
    if (mode == 0) { if (cfg == 1) GL(0, 64, 32); else GL(0, 32, 32); }
    else if (mode == 1) { if (cfg == 1) GL(1, 64, 32); else GL(1, 32, 32); }
    else { if (cfg == 1) GL(2, 64, 32); else GL(2, 32, 32); }
#undef GL
    if (S > 1) {
      long MN = (long)M * N;
      dim3 rg((MN / 4 + 255) / 256);
      if (mode == 0)
        sk_reduce_kernel<0><<<rg, 256, 0, stream>>>(pbuf, S, MN, N, bias, bOff, res, C, out_mode, dflag);
      else if (mode == 1)
        sk_reduce_kernel<1><<<rg, 256, 0, stream>>>(pbuf, S, MN, N, bias, bOff, res, C, out_mode, dflag);
      else
        sk_reduce_kernel<2><<<rg, 256, 0, stream>>>(pbuf, S, MN, N, bias, bOff, res, C, out_mode, dflag);
    }
  };

  // ---- patchify (visible patches only) ----
  {
    int tot = M_VIS * 768;
    im2col_vis_kernel<<<(tot + 255) / 256, 256, 0, stream>>>(d_in[0], unmasked, im2col, dflag);
    gemm(0, 2, 2, im2col, d_in[3], 0, d_in[4], 0, nullptr, vis, 3136, D_, 768, 0);
    int tot2 = B_ * SENC_ * D_;
    build_xe_kernel<<<(tot2 + 255) / 256, 256, 0, stream>>>(vis, d_in[5], d_in[6], unmasked, xe, dflag);
  }

  // ---- encoder: 6 blocks, S=50, D=384, H=6, dh=64 ----
  for (int i = 0; i < 6; i++) {
    ln_kernel<D_><<<M_ENC / 4, 256, 0, stream>>>(xe, d_in[7], (long)i * D_, d_in[8], (long)i * D_, t0, M_ENC, dflag);
    gemm(0, 1, 1, t0, d_in[9], (long)i * 3 * D_ * D_, d_in[10], (long)i * 3 * D_, nullptr, big, M_ENC, 3 * D_, D_, 0);
    attn_enc_kernel<<<B_ * 6, 128, 0, stream>>>(big, t0);
    gemm(2, 2, 2, t0, d_in[11], (long)i * D_ * D_, d_in[12], (long)i * D_, xe, xe, M_ENC, D_, D_, 1);
    ln_kernel<D_><<<M_ENC / 4, 256, 0, stream>>>(xe, d_in[13], (long)i * D_, d_in[14], (long)i * D_, t0, M_ENC, dflag);
    gemm(1, 1, 1, t0, d_in[15], (long)i * 4 * D_ * D_, d_in[16], (long)i * 4 * D_, nullptr, big, M_ENC, 4 * D_, D_, 0);
    gemm(2, 1, 4, big, d_in[17], (long)i * D_ * 4 * D_, d_in[18], (long)i * D_, xe, xe, M_ENC, D_, 4 * D_, 1);
  }
  ln_kernel<D_><<<M_ENC / 4, 256, 0, stream>>>(xe, d_in[19], 0, d_in[20], 0, t0, M_ENC, dflag);
  gemm(0, 2, 2, t0, d_in[21], 0, d_in[22], 0, nullptr, xd, M_ENC, DD_, D_, 0);

  // ---- assemble decoder input ----
  {
    int tot = B_ * NP_ * DD_;
    dec_init_kernel<<<(tot + 255) / 256, 256, 0, stream>>>(d_in[23], d_in[24], full, dflag);
    int tot2 = B_ * NVIS_ * DD_;
    dec_scatter_kernel<<<(tot2 + 255) / 256, 256, 0, stream>>>(xd, unmasked, d_in[24], full, dflag);
  }

  // ---- decoder: 4 blocks, S=196, D=256, H=8, dh=32 ----
  for (int i = 0; i < 4; i++) {
    ln_kernel<DD_><<<M_DEC / 4, 256, 0, stream>>>(full, d_in[25], (long)i * DD_, d_in[26], (long)i * DD_, t0, M_DEC, dflag);
    gemm(0, 1, 1, t0, d_in[27], (long)i * 3 * DD_ * DD_, d_in[28], (long)i * 3 * DD_, nullptr, big, M_DEC, 3 * DD_, DD_, 0);
    attn_dec_kernel<<<B_ * 8, 256, 0, stream>>>(big, t0);
    gemm(2, 1, 1, t0, d_in[29], (long)i * DD_ * DD_, d_in[30], (long)i * DD_, full, full, M_DEC, DD_, DD_, 1);
    ln_kernel<DD_><<<M_DEC / 4, 256, 0, stream>>>(full, d_in[31], (long)i * DD_, d_in[32], (long)i * DD_, t0, M_DEC, dflag);
    gemm(1, 1, 1, t0, d_in[33], (long)i * 4 * DD_ * DD_, d_in[34], (long)i * 4 * DD_, nullptr, big, M_DEC, 4 * DD_, DD_, 0);
    gemm(2, 1, 1, big, d_in[35], (long)i * DD_ * 4 * DD_, d_in[36], (long)i * DD_, full, full, M_DEC, DD_, 4 * DD_, 1);
  }
  ln_kernel<DD_><<<M_DEC / 4, 256, 0, stream>>>(full, d_in[37], 0, d_in[38], 0, t0, M_DEC, dflag);

  // ---- predictor head ----
  gemm(0, 1, 1, t0, d_in[39], 0, d_in[40], 0, nullptr, d_out, M_DEC, 768, DD_, 2);
}